// Round 1
// baseline (220.275 us; speedup 1.0000x reference)
//
#include <hip/hip_runtime.h>
#include <hip/hip_bf16.h>

// Problem dims (fixed by reference setup_inputs)
static constexpr int BATCH = 4096;  // M
static constexpr int DIN   = 2048;  // K of GEMM1
static constexpr int HDIM  = 2048;  // N1 = K2 = N2
static constexpr int ADIM  = 5;
static constexpr int TSTEPS = 10;

typedef __attribute__((ext_vector_type(8))) short short8;
typedef __attribute__((ext_vector_type(4))) float floatx4;

// ---- bf16 helpers (RNE, no dependence on __hip_bfloat16 internals) ----
__device__ __forceinline__ unsigned short f2bf(float f) {
  unsigned int u = __float_as_uint(f);
  unsigned int r = (u + 0x7fffu + ((u >> 16) & 1u)) >> 16;
  return (unsigned short)r;
}
__device__ __forceinline__ float bf2f(unsigned short u) {
  return __uint_as_float(((unsigned int)u) << 16);
}

// ---- 1) fp32 -> bf16 elementwise (vectorized) ----
__global__ __launch_bounds__(256) void k_cvt(const float4* __restrict__ in,
                                             ushort4* __restrict__ out, int n4) {
  int i = blockIdx.x * 256 + threadIdx.x;
  if (i < n4) {
    float4 v = in[i];
    ushort4 o;
    o.x = f2bf(v.x); o.y = f2bf(v.y); o.z = f2bf(v.z); o.w = f2bf(v.w);
    out[i] = o;
  }
}

// ---- 2) fp32 [n][n] -> transposed bf16 [n][n]: out[a][b] = in[b][a] ----
__global__ __launch_bounds__(256) void k_transpose_cvt(const float* __restrict__ in,
                                                       unsigned short* __restrict__ out,
                                                       int n) {
  __shared__ float tl[32][33];
  int c0 = blockIdx.x * 32, r0 = blockIdx.y * 32;
  int tx = threadIdx.x, ty = threadIdx.y;  // 32 x 8
  #pragma unroll
  for (int s = 0; s < 32; s += 8)
    tl[ty + s][tx] = in[(size_t)(r0 + ty + s) * n + (c0 + tx)];
  __syncthreads();
  #pragma unroll
  for (int s = 0; s < 32; s += 8)
    out[(size_t)(c0 + ty + s) * n + (r0 + tx)] = f2bf(tl[tx][ty + s]);
}

// ---- 3) bf16 MFMA GEMM, m97 structure: 128x128 tile, BK=64, 4 waves ----
// A: [M][K] bf16 row-major; BT: [N][K] bf16 (B transposed); C = A*B + bias.
// MODE 0: store bf16(acc + bias)          (GEMM1 -> h)
// MODE 1: LIF 10-step on (acc + bias), store bf16(spike count 0..10) (GEMM2)
// LDS tiles are XOR-swizzled (16B slot ^= row&7) via pre-swizzled per-lane
// global source addresses; global_load_lds dest stays linear (guide m173).
template <int MODE>
__global__ __launch_bounds__(256) void k_gemm(const unsigned short* __restrict__ Ag,
                                              const unsigned short* __restrict__ BTg,
                                              const float* __restrict__ bias,
                                              unsigned short* __restrict__ outb,
                                              int M, int N, int K) {
  constexpr int BM = 128, BN = 128, BK = 64;
  __shared__ unsigned short Al[BM * BK];  // 16 KB
  __shared__ unsigned short Bl[BN * BK];  // 16 KB

  const int nbn = N / BN;
  const int nwg = gridDim.x;
  const int wg = blockIdx.x;
  // bijective XCD swizzle (nwg % 8 == 0 for our launches)
  const int cpx = nwg >> 3;
  const int swz = (wg & 7) * cpx + (wg >> 3);
  const int bm = swz / nbn, bn = swz % nbn;
  const int m0 = bm * BM, n0 = bn * BN;

  const int t = threadIdx.x;
  const int l = t & 63;
  const int w = t >> 6;
  const int wrow = w >> 1, wcol = w & 1;

  // staging: thread t, instr j covers LDS phys bytes [t*16 + j*4096, +16)
  // phys row = t/8 + j*32 ; phys 16B-slot = t&7 ; logical slot = (t&7)^(row&7)
  const int srow = t >> 3;  // + j*32 per instr
  const int scol = (((t & 7) ^ ((t >> 3) & 7)) << 3);  // bf16 elements
  const unsigned short* gA = Ag + (size_t)(m0 + srow) * K + scol;
  const unsigned short* gB = BTg + (size_t)(n0 + srow) * K + scol;

  // ds_read fragment addressing (swizzled): lane reads 16B at
  //   row*128 + ((kslot ^ (row&7)) << 4), row&7 == l&7 here.
  const int slotbase = (l >> 4) ^ (l & 7);
  const int baseA = (wrow * 64 + (l & 15)) * 128;
  const int baseB = (wcol * 64 + (l & 15)) * 128;

  floatx4 acc[4][4] = {};

  for (int kt = 0; kt < K; kt += BK) {
    __syncthreads();
    #pragma unroll
    for (int j = 0; j < 4; ++j) {
      __builtin_amdgcn_global_load_lds(
          (const __attribute__((address_space(1))) void*)(gA + (size_t)j * 32 * K + kt),
          (__attribute__((address_space(3))) void*)((char*)Al + t * 16 + j * 4096),
          16, 0, 0);
    }
    #pragma unroll
    for (int j = 0; j < 4; ++j) {
      __builtin_amdgcn_global_load_lds(
          (const __attribute__((address_space(1))) void*)(gB + (size_t)j * 32 * K + kt),
          (__attribute__((address_space(3))) void*)((char*)Bl + t * 16 + j * 4096),
          16, 0, 0);
    }
    __syncthreads();

    #pragma unroll
    for (int kkb = 0; kkb <= 4; kkb += 4) {  // kslot base 0 -> k[0,32), 4 -> k[32,64)
      short8 af[4], bfr[4];
      const int so = ((kkb ^ slotbase) << 4);
      #pragma unroll
      for (int i = 0; i < 4; ++i)
        af[i] = *(const short8*)((const char*)Al + baseA + i * 2048 + so);
      #pragma unroll
      for (int i = 0; i < 4; ++i)
        bfr[i] = *(const short8*)((const char*)Bl + baseB + i * 2048 + so);
      #pragma unroll
      for (int i = 0; i < 4; ++i)
        #pragma unroll
        for (int jj = 0; jj < 4; ++jj)
          acc[i][jj] = __builtin_amdgcn_mfma_f32_16x16x32_bf16(af[i], bfr[jj],
                                                               acc[i][jj], 0, 0, 0);
    }
  }

  // epilogue: C/D layout col = l&15, row = (l>>4)*4 + r  (guide m89/m91)
  const int crow = m0 + wrow * 64 + ((l >> 4) << 2);
  const int ccol = n0 + wcol * 64 + (l & 15);
  #pragma unroll
  for (int jj = 0; jj < 4; ++jj) {
    const int col = ccol + jj * 16;
    const float bv = bias[col];
    #pragma unroll
    for (int i = 0; i < 4; ++i) {
      const int row = crow + i * 16;
      #pragma unroll
      for (int r = 0; r < 4; ++r) {
        float v = acc[i][jj][r] + bv;
        if (MODE == 1) {
          // LIF, decay_input=True, tau=2, v_th=1, hard reset to 0, T=10 steps
          float vm = 0.f;
          int cnt = 0;
          #pragma unroll
          for (int s = 0; s < TSTEPS; ++s) {
            vm = vm + (v - vm) * 0.5f;
            int sp = (vm - 1.0f >= 0.0f) ? 1 : 0;
            cnt += sp;
            vm = sp ? 0.0f : vm;
          }
          v = (float)cnt;  // integer 0..10, exact in bf16
        }
        outb[(size_t)(row + r) * N + col] = f2bf(v);
      }
    }
  }
}

// ---- 4) head: pre = 0.1*(cnt @ W_out) + b_out ; out = (pre/2 - 1 >= 0) ----
__global__ __launch_bounds__(256) void k_head(const unsigned short* __restrict__ cntb,
                                              const float* __restrict__ Wout,
                                              const float* __restrict__ bout,
                                              float* __restrict__ out) {
  __shared__ float Wl[HDIM * ADIM];  // 40 KB
  const int t = threadIdx.x;
  for (int i = t; i < HDIM * ADIM; i += 256) Wl[i] = Wout[i];
  __syncthreads();
  const int w = t >> 6, l = t & 63;
  const int row = blockIdx.x * 4 + w;
  const unsigned short* rp = cntb + (size_t)row * HDIM;
  float acc[ADIM] = {};
  #pragma unroll
  for (int it = 0; it < 4; ++it) {
    const int k0 = it * 512 + l * 8;
    short8 v = *(const short8*)(rp + k0);
    #pragma unroll
    for (int jj = 0; jj < 8; ++jj) {
      const float c = bf2f((unsigned short)v[jj]);
      const int k = k0 + jj;
      #pragma unroll
      for (int a = 0; a < ADIM; ++a) acc[a] += c * Wl[k * ADIM + a];
    }
  }
  #pragma unroll
  for (int a = 0; a < ADIM; ++a)
    #pragma unroll
    for (int off = 32; off >= 1; off >>= 1)
      acc[a] += __shfl_down(acc[a], off, 64);
  if (l == 0) {
    #pragma unroll
    for (int a = 0; a < ADIM; ++a) {
      const float pre = acc[a] * 0.1f + bout[a];
      const float vout = pre * 0.5f;  // single-step LIF from v=0: v = pre/tau
      out[(size_t)row * ADIM + a] = (vout - 1.0f >= 0.0f) ? 1.0f : 0.0f;
    }
  }
}

extern "C" void kernel_launch(void* const* d_in, const int* in_sizes, int n_in,
                              void* d_out, int out_size, void* d_ws, size_t ws_size,
                              hipStream_t stream) {
  const float* x     = (const float*)d_in[0];
  const float* W_in  = (const float*)d_in[1];
  const float* b_in  = (const float*)d_in[2];
  const float* W_snn = (const float*)d_in[3];
  const float* b_snn = (const float*)d_in[4];
  const float* W_out = (const float*)d_in[5];
  const float* b_out = (const float*)d_in[6];
  float* out = (float*)d_out;

  // workspace layout (48 MB total):
  // [0,16M)   xb   : bf16 x [4096][2048]   (reused later for spike counts)
  // [16M,24M) WinT : bf16 W_in^T [2048][2048]
  // [24M,32M) WsnT : bf16 W_snn^T [2048][2048]
  // [32M,48M) hb   : bf16 h [4096][2048]
  char* ws = (char*)d_ws;
  unsigned short* xb   = (unsigned short*)(ws);
  unsigned short* WinT = (unsigned short*)(ws + (size_t)16 * 1024 * 1024);
  unsigned short* WsnT = (unsigned short*)(ws + (size_t)24 * 1024 * 1024);
  unsigned short* hb   = (unsigned short*)(ws + (size_t)32 * 1024 * 1024);
  unsigned short* cntb = xb;  // x no longer needed after GEMM1

  // 1) x -> bf16
  const int n4 = BATCH * DIN / 4;
  k_cvt<<<(n4 + 255) / 256, 256, 0, stream>>>((const float4*)x, (ushort4*)xb, n4);

  // 2) W_in, W_snn -> transposed bf16
  dim3 tb(32, 8);
  dim3 tg(DIN / 32, HDIM / 32);
  k_transpose_cvt<<<tg, tb, 0, stream>>>(W_in, WinT, DIN);
  k_transpose_cvt<<<tg, tb, 0, stream>>>(W_snn, WsnT, HDIM);

  // 3) h = x @ W_in + b_in  (bf16 out)
  const int gblk = (BATCH / 128) * (HDIM / 128);  // 512, %8 == 0
  k_gemm<0><<<gblk, 256, 0, stream>>>(xb, WinT, b_in, hb, BATCH, HDIM, DIN);

  // 4) cur = h @ W_snn + b_snn ; fused 10-step LIF -> spike counts
  k_gemm<1><<<gblk, 256, 0, stream>>>(hb, WsnT, b_snn, cntb, BATCH, HDIM, HDIM);

  // 5) output head + output LIF threshold
  k_head<<<BATCH / 4, 256, 0, stream>>>(cntb, W_out, b_out, out);
}

// Round 2
// 211.682 us; speedup vs baseline: 1.0406x; 1.0406x over previous
//
#include <hip/hip_runtime.h>
#include <hip/hip_bf16.h>

// Problem dims (fixed by reference setup_inputs)
static constexpr int BATCH = 4096;  // M
static constexpr int DIN   = 2048;  // K of GEMM1
static constexpr int HDIM  = 2048;  // N1 = K2 = N2
static constexpr int ADIM  = 5;

typedef __attribute__((ext_vector_type(8))) short short8;
typedef __attribute__((ext_vector_type(4))) float floatx4;

// ---- bf16 helpers (RNE) ----
__device__ __forceinline__ unsigned short f2bf(float f) {
  unsigned int u = __float_as_uint(f);
  unsigned int r = (u + 0x7fffu + ((u >> 16) & 1u)) >> 16;
  return (unsigned short)r;
}
__device__ __forceinline__ float bf2f(unsigned short u) {
  return __uint_as_float(((unsigned int)u) << 16);
}

// ---- 1) fp32 -> bf16 elementwise (vectorized) ----
__global__ __launch_bounds__(256) void k_cvt(const float4* __restrict__ in,
                                             ushort4* __restrict__ out, int n4) {
  int i = blockIdx.x * 256 + threadIdx.x;
  if (i < n4) {
    float4 v = in[i];
    ushort4 o;
    o.x = f2bf(v.x); o.y = f2bf(v.y); o.z = f2bf(v.z); o.w = f2bf(v.w);
    out[i] = o;
  }
}

// ---- 2) fp32 [n][n] -> transposed bf16 [n][n]: out[a][b] = in[b][a] ----
__global__ __launch_bounds__(256) void k_transpose_cvt(const float* __restrict__ in,
                                                       unsigned short* __restrict__ out,
                                                       int n) {
  __shared__ float tl[32][33];
  int c0 = blockIdx.x * 32, r0 = blockIdx.y * 32;
  int tx = threadIdx.x, ty = threadIdx.y;  // 32 x 8
  #pragma unroll
  for (int s = 0; s < 32; s += 8)
    tl[ty + s][tx] = in[(size_t)(r0 + ty + s) * n + (c0 + tx)];
  __syncthreads();
  #pragma unroll
  for (int s = 0; s < 32; s += 8)
    out[(size_t)(c0 + ty + s) * n + (r0 + tx)] = f2bf(tl[tx][ty + s]);
}

// ---- 3) bf16 MFMA GEMM, 8-phase-style schedule ----
// BM=256, BN=128, BK=64; 512 threads = 8 waves (4M x 2N), per-wave 64x64.
// 3-buffer LDS (144 KiB), prefetch 2 K-tiles ahead, counted s_waitcnt vmcnt(6)
// at tile boundaries (never 0 in steady state). LDS tiles XOR-swizzled
// (16B slot ^= row&7) via pre-swizzled per-lane global source addresses;
// global_load_lds dest stays linear (verified in R1: BANK_CONFLICT == 0).
// A: [M][K] bf16 row-major; BT: [N][K] bf16 (B transposed); C = A*B + bias.
// MODE 0: store bf16(acc + bias)                      (GEMM1 -> h)
// MODE 1: LIF count over 10 steps (closed form), bf16 (GEMM2 -> spike counts)
template <int MODE>
__global__ __launch_bounds__(512, 2) void k_gemm(const unsigned short* __restrict__ Ag,
                                                 const unsigned short* __restrict__ BTg,
                                                 const float* __restrict__ bias,
                                                 unsigned short* __restrict__ outb,
                                                 int M, int N, int K) {
  constexpr int BM = 256, BN = 128, BK = 64;
  __shared__ unsigned short Al[3][BM * BK];  // 3 x 32 KiB
  __shared__ unsigned short Bl[3][BN * BK];  // 3 x 16 KiB  (total 144 KiB)

  const int nbn = N / BN;            // 16
  const int nwg = gridDim.x;         // 256 (%8==0 -> bijective XCD swizzle)
  const int wg  = blockIdx.x;
  const int cpx = nwg >> 3;
  const int swz = (wg & 7) * cpx + (wg >> 3);
  const int bm = swz / nbn, bn = swz % nbn;
  const int m0 = bm * BM, n0 = bn * BN;

  const int t = threadIdx.x;
  const int l = t & 63;
  const int w = t >> 6;        // 0..7
  const int wrow = w >> 1;     // 0..3 (M)
  const int wcol = w & 1;      // 0..1 (N)

  // staging: per instr, 512 threads x 16B = 8 KiB chunk = 64 LDS rows.
  // phys row = t/8 (+64 per j); phys 16B-slot = t&7; logical slot = phys^row&7
  const int srow = t >> 3;
  const int scol = (((t & 7) ^ (srow & 7)) << 3);  // bf16 elements
  const unsigned short* gA = Ag + (size_t)(m0 + srow) * K + scol;
  const unsigned short* gB = BTg + (size_t)(n0 + srow) * K + scol;

  const int NT = K / BK;  // 32

  auto stageA = [&](int tt) {
    const int kt = tt * BK;
    char* dst = (char*)&Al[tt % 3][0] + t * 16;
    #pragma unroll
    for (int j = 0; j < 4; ++j)
      __builtin_amdgcn_global_load_lds(
          (const __attribute__((address_space(1))) void*)(gA + (size_t)j * 64 * K + kt),
          (__attribute__((address_space(3))) void*)(dst + j * 8192), 16, 0, 0);
  };
  auto stageB = [&](int tt) {
    const int kt = tt * BK;
    char* dst = (char*)&Bl[tt % 3][0] + t * 16;
    #pragma unroll
    for (int j = 0; j < 2; ++j)
      __builtin_amdgcn_global_load_lds(
          (const __attribute__((address_space(1))) void*)(gB + (size_t)j * 64 * K + kt),
          (__attribute__((address_space(3))) void*)(dst + j * 8192), 16, 0, 0);
  };

  // fragment read bases (swizzled): row*128 + ((kslot ^ (row&7))<<4)
  const int rA = wrow * 64 + (l & 15);  // + i*16 per frag (i*16 % 8 == 0)
  const int rB = wcol * 64 + (l & 15);
  const int kl = l >> 4;  // 0..3

  floatx4 acc[4][4] = {};

  // prologue: tiles 0 and 1 in flight; wait tile 0 (leave 6 outstanding)
  stageA(0); stageB(0);
  stageA(1); stageB(1);
  asm volatile("s_waitcnt vmcnt(6)" ::: "memory");
  __builtin_amdgcn_s_barrier();

  for (int tt = 0; tt < NT; ++tt) {
    const unsigned short* Ab = &Al[tt % 3][0];
    const unsigned short* Bb = &Bl[tt % 3][0];
    const bool pre = (tt + 2 < NT);
    #pragma unroll
    for (int p = 0; p < 2; ++p) {  // K-half phases: k[0,32), k[32,64)
      short8 af[4], bfv[4];
      const int soA = ((((p << 2) | kl) ^ (rA & 7)) << 4);
      const int soB = ((((p << 2) | kl) ^ (rB & 7)) << 4);
      #pragma unroll
      for (int i = 0; i < 4; ++i)
        af[i] = *(const short8*)((const char*)Ab + rA * 128 + i * 2048 + soA);
      #pragma unroll
      for (int i = 0; i < 4; ++i)
        bfv[i] = *(const short8*)((const char*)Bb + rB * 128 + i * 2048 + soB);
      if (p == 0) { if (pre) stageA(tt + 2); }
      else        { if (pre) stageB(tt + 2); }
      __builtin_amdgcn_s_barrier();
      __builtin_amdgcn_s_setprio(1);
      #pragma unroll
      for (int i = 0; i < 4; ++i)
        #pragma unroll
        for (int jj = 0; jj < 4; ++jj)
          acc[i][jj] = __builtin_amdgcn_mfma_f32_16x16x32_bf16(af[i], bfv[jj],
                                                               acc[i][jj], 0, 0, 0);
      __builtin_amdgcn_s_setprio(0);
      if (p == 0) {
        __builtin_amdgcn_s_barrier();
      } else {
        // tile boundary: ensure tile tt+1 staged. outstanding = (tt+1)'s 6
        // (+ (tt+2)'s 6 if issued). FIFO -> wait leaves the newest 6.
        if (tt + 2 < NT)      asm volatile("s_waitcnt vmcnt(6)" ::: "memory");
        else if (tt + 1 < NT) asm volatile("s_waitcnt vmcnt(0)" ::: "memory");
        if (tt + 1 < NT) __builtin_amdgcn_s_barrier();
      }
    }
  }

  // epilogue: C/D layout col = l&15, row = (l>>4)*4 + r
  const int crow = m0 + wrow * 64 + ((l >> 4) << 2);
  const int ccol = n0 + wcol * 64 + (l & 15);
  #pragma unroll
  for (int jj = 0; jj < 4; ++jj) {
    const int col = ccol + jj * 16;
    const float bv = bias[col];
    #pragma unroll
    for (int i = 0; i < 4; ++i) {
      const int row = crow + i * 16;
      #pragma unroll
      for (int r = 0; r < 4; ++r) {
        float v = acc[i][jj][r] + bv;
        if (MODE == 1) {
          // LIF (tau=2, v_th=1, hard reset, v0=0, T=10) with CONSTANT input v:
          // from v=0, v_k = v*(1-2^-k); first spike at k1 = min k: v_k >= 1,
          // reset repeats the identical sequence -> period k1, count=floor(10/k1).
          // Thresholds c_k = 1/(1-2^-k); count: k1=1->10, 2->5, 3->3, 4..5->2,
          // 6..10->1, never->0.
          float c;
          c = (v >= 2.0f)                  ? 10.f
            : (v >= 1.3333333333333333f)   ? 5.f
            : (v >= 1.1428571428571428f)   ? 3.f
            : (v >= 1.0322580645161290f)   ? 2.f
            : (v >= 1.0009775171065494f)   ? 1.f : 0.f;
          v = c;
        }
        outb[(size_t)(row + r) * N + col] = f2bf(v);
      }
    }
  }
}

// ---- 4) head: pre = 0.1*(cnt @ W_out) + b_out ; out = (pre/2 - 1 >= 0) ----
__global__ __launch_bounds__(256) void k_head(const unsigned short* __restrict__ cntb,
                                              const float* __restrict__ Wout,
                                              const float* __restrict__ bout,
                                              float* __restrict__ out) {
  __shared__ float Wl[HDIM * ADIM];  // 40 KB
  const int t = threadIdx.x;
  for (int i = t; i < HDIM * ADIM; i += 256) Wl[i] = Wout[i];
  __syncthreads();
  const int w = t >> 6, l = t & 63;
  const int row = blockIdx.x * 4 + w;
  const unsigned short* rp = cntb + (size_t)row * HDIM;
  float acc[ADIM] = {};
  #pragma unroll
  for (int it = 0; it < 4; ++it) {
    const int k0 = it * 512 + l * 8;
    short8 v = *(const short8*)(rp + k0);
    #pragma unroll
    for (int jj = 0; jj < 8; ++jj) {
      const float c = bf2f((unsigned short)v[jj]);
      const int k = k0 + jj;
      #pragma unroll
      for (int a = 0; a < ADIM; ++a) acc[a] += c * Wl[k * ADIM + a];
    }
  }
  #pragma unroll
  for (int a = 0; a < ADIM; ++a)
    #pragma unroll
    for (int off = 32; off >= 1; off >>= 1)
      acc[a] += __shfl_down(acc[a], off, 64);
  if (l == 0) {
    #pragma unroll
    for (int a = 0; a < ADIM; ++a) {
      const float pre = acc[a] * 0.1f + bout[a];
      const float vout = pre * 0.5f;  // single-step LIF from v=0: v = pre/tau
      out[(size_t)row * ADIM + a] = (vout - 1.0f >= 0.0f) ? 1.0f : 0.0f;
    }
  }
}

extern "C" void kernel_launch(void* const* d_in, const int* in_sizes, int n_in,
                              void* d_out, int out_size, void* d_ws, size_t ws_size,
                              hipStream_t stream) {
  const float* x     = (const float*)d_in[0];
  const float* W_in  = (const float*)d_in[1];
  const float* b_in  = (const float*)d_in[2];
  const float* W_snn = (const float*)d_in[3];
  const float* b_snn = (const float*)d_in[4];
  const float* W_out = (const float*)d_in[5];
  const float* b_out = (const float*)d_in[6];
  float* out = (float*)d_out;

  // workspace layout (48 MB total):
  // [0,16M)   xb   : bf16 x [4096][2048]   (reused later for spike counts)
  // [16M,24M) WinT : bf16 W_in^T [2048][2048]
  // [24M,32M) WsnT : bf16 W_snn^T [2048][2048]
  // [32M,48M) hb   : bf16 h [4096][2048]
  char* ws = (char*)d_ws;
  unsigned short* xb   = (unsigned short*)(ws);
  unsigned short* WinT = (unsigned short*)(ws + (size_t)16 * 1024 * 1024);
  unsigned short* WsnT = (unsigned short*)(ws + (size_t)24 * 1024 * 1024);
  unsigned short* hb   = (unsigned short*)(ws + (size_t)32 * 1024 * 1024);
  unsigned short* cntb = xb;  // x no longer needed after GEMM1

  // 1) x -> bf16
  const int n4 = BATCH * DIN / 4;
  k_cvt<<<(n4 + 255) / 256, 256, 0, stream>>>((const float4*)x, (ushort4*)xb, n4);

  // 2) W_in, W_snn -> transposed bf16
  dim3 tb(32, 8);
  dim3 tg(DIN / 32, HDIM / 32);
  k_transpose_cvt<<<tg, tb, 0, stream>>>(W_in, WinT, DIN);
  k_transpose_cvt<<<tg, tb, 0, stream>>>(W_snn, WsnT, HDIM);

  // 3) h = x @ W_in + b_in  (bf16 out)
  const int gblk = (BATCH / 256) * (HDIM / 128);  // 16*16 = 256 WGs, 1/CU
  k_gemm<0><<<gblk, 512, 0, stream>>>(xb, WinT, b_in, hb, BATCH, HDIM, DIN);

  // 4) cur = h @ W_snn + b_snn ; fused 10-step LIF -> spike counts
  k_gemm<1><<<gblk, 512, 0, stream>>>(hb, WsnT, b_snn, cntb, BATCH, HDIM, HDIM);

  // 5) output head + output LIF threshold
  k_head<<<BATCH / 4, 256, 0, stream>>>(cntb, W_out, b_out, out);
}

// Round 3
// 199.339 us; speedup vs baseline: 1.1050x; 1.0619x over previous
//
#include <hip/hip_runtime.h>
#include <hip/hip_bf16.h>

// Problem dims (fixed by reference setup_inputs)
static constexpr int BATCH = 4096;  // M
static constexpr int DIN   = 2048;  // K of GEMM1
static constexpr int HDIM  = 2048;  // N1 = K2 = N2
static constexpr int ADIM  = 5;

typedef __attribute__((ext_vector_type(8))) short short8;
typedef __attribute__((ext_vector_type(4))) float floatx4;

// ---- bf16 helpers (RNE) ----
__device__ __forceinline__ unsigned short f2bf(float f) {
  unsigned int u = __float_as_uint(f);
  unsigned int r = (u + 0x7fffu + ((u >> 16) & 1u)) >> 16;
  return (unsigned short)r;
}
__device__ __forceinline__ float bf2f(unsigned short u) {
  return __uint_as_float(((unsigned int)u) << 16);
}

// ---- 1) fused prep: x->bf16 (8192 blocks) + 2 transposes (4096 each) ----
__global__ __launch_bounds__(256) void k_prep(const float* __restrict__ x,
                                              const float* __restrict__ W_in,
                                              const float* __restrict__ W_snn,
                                              unsigned short* __restrict__ xb,
                                              unsigned short* __restrict__ WinT,
                                              unsigned short* __restrict__ WsnT) {
  __shared__ float tl[32][33];
  const int b = blockIdx.x;
  if (b < 8192) {
    // cvt x: 8192 * 256 * 4 = 4096*2048 elems
    const int i = b * 256 + threadIdx.x;
    float4 v = ((const float4*)x)[i];
    ushort4 o;
    o.x = f2bf(v.x); o.y = f2bf(v.y); o.z = f2bf(v.z); o.w = f2bf(v.w);
    ((ushort4*)xb)[i] = o;
  } else {
    int bi = b - 8192;
    const float* src;
    unsigned short* dst;
    if (bi < 4096) { src = W_in; dst = WinT; }
    else           { src = W_snn; dst = WsnT; bi -= 4096; }
    const int bx = bi & 63, by = bi >> 6;
    const int c0 = bx * 32, r0 = by * 32;
    const int tx = threadIdx.x & 31, ty = threadIdx.x >> 5;
    #pragma unroll
    for (int s = 0; s < 32; s += 8)
      tl[ty + s][tx] = src[(size_t)(r0 + ty + s) * 2048 + (c0 + tx)];
    __syncthreads();
    #pragma unroll
    for (int s = 0; s < 32; s += 8)
      dst[(size_t)(c0 + ty + s) * 2048 + (r0 + tx)] = f2bf(tl[tx][ty + s]);
  }
}

// ---- 2) bf16 MFMA GEMM: 128x128 tile, BK=64, 4 waves = 1M x 2N x 2KK ----
// Each wave computes a 128x64 output with HALF the K-slots (kk-split);
// pair-sum epilogue through LDS combines kk halves. Double-buffered LDS
// (2 x 32 KB), stage tile t+1 at top of tile t, ONE __syncthreads per tile.
// 2 blocks/CU. LDS XOR-swizzle (16B slot ^= row&7) via pre-swizzled global
// source addresses; verified 0 bank conflicts in R1/R2.
// A: [M][K] bf16 row-major; BT: [N][K] bf16; C = A*B + bias.
// MODE 0: store bf16(acc+bias).  MODE 1: 10-step LIF closed form -> count.
template <int MODE>
__global__ __launch_bounds__(256, 2) void k_gemm(const unsigned short* __restrict__ Ag,
                                                 const unsigned short* __restrict__ BTg,
                                                 const float* __restrict__ bias,
                                                 unsigned short* __restrict__ outb,
                                                 int M, int N, int K) {
  constexpr int BK = 64;
  // [buf][ A: ushort 0..8191 | B: ushort 8192..16383 ]  = 64 KB total
  __shared__ unsigned short smem[2][16384];

  const int nbn = N / 128;
  const int nwg = gridDim.x;  // 512, %8==0 -> bijective XCD swizzle
  const int wg  = blockIdx.x;
  const int cpx = nwg >> 3;
  const int swz = (wg & 7) * cpx + (wg >> 3);
  const int bm = swz / nbn, bn = swz % nbn;
  const int m0 = bm * 128, n0 = bn * 128;

  const int t = threadIdx.x;
  const int l = t & 63;
  const int w = t >> 6;      // 0..3
  const int wc  = w & 1;     // N-half
  const int kkh = w >> 1;    // K-half (kk-split)

  // staging: thread t, instr j -> LDS bytes [t*16 + j*4096, +16) (linear dest)
  // phys row = t/8 + j*32 ; phys slot = t&7 ; source K-group = slot ^ (row&7)
  const int srow = t >> 3;
  const int sg = (((t & 7) ^ (srow & 7)) << 3);  // bf16 elems
  const unsigned short* gA = Ag + (size_t)(m0 + srow) * K + sg;
  const unsigned short* gB = BTg + (size_t)(n0 + srow) * K + sg;

  const int NT = K / BK;  // 32

  auto stage = [&](int tt) {
    const int kt = tt * BK;
    char* base = (char*)&smem[tt & 1][0];
    #pragma unroll
    for (int j = 0; j < 4; ++j)
      __builtin_amdgcn_global_load_lds(
          (const __attribute__((address_space(1))) void*)(gA + (size_t)j * 32 * K + kt),
          (__attribute__((address_space(3))) void*)(base + t * 16 + j * 4096), 16, 0, 0);
    #pragma unroll
    for (int j = 0; j < 4; ++j)
      __builtin_amdgcn_global_load_lds(
          (const __attribute__((address_space(1))) void*)(gB + (size_t)j * 32 * K + kt),
          (__attribute__((address_space(3))) void*)(base + 16384 + t * 16 + j * 4096), 16, 0, 0);
  };

  // fragment read addressing (swizzled): byte = row*128 + ((slot ^ (row&7))<<4)
  // wave reads K-slots slot = kkh*4 + (l>>4); all its rows have row&7 == l&7.
  const int soff = (((kkh << 2) | (l >> 4)) ^ (l & 7)) << 4;
  const int rA0 = (l & 15) * 128;                  // + i*16*128
  const int rB0 = (wc * 64 + (l & 15)) * 128;      // + j*16*128

  floatx4 acc[8][4] = {};

  stage(0);
  __syncthreads();

  for (int tt = 0; tt < NT; ++tt) {
    if (tt + 1 < NT) stage(tt + 1);
    const char* Ab = (const char*)&smem[tt & 1][0];
    const char* Bb = Ab + 32768;  // byte offset of B region (8192 ushorts)
    short8 bf[4];
    #pragma unroll
    for (int j = 0; j < 4; ++j)
      bf[j] = *(const short8*)(Bb + rB0 + j * 2048 + soff);
    // phase a: M-frags 0..3
    {
      short8 af[4];
      #pragma unroll
      for (int i = 0; i < 4; ++i)
        af[i] = *(const short8*)(Ab + rA0 + i * 2048 + soff);
      #pragma unroll
      for (int i = 0; i < 4; ++i)
        #pragma unroll
        for (int j = 0; j < 4; ++j)
          acc[i][j] = __builtin_amdgcn_mfma_f32_16x16x32_bf16(af[i], bf[j],
                                                              acc[i][j], 0, 0, 0);
    }
    // phase b: M-frags 4..7
    {
      short8 af[4];
      #pragma unroll
      for (int i = 0; i < 4; ++i)
        af[i] = *(const short8*)(Ab + rA0 + (i + 4) * 2048 + soff);
      #pragma unroll
      for (int i = 0; i < 4; ++i)
        #pragma unroll
        for (int j = 0; j < 4; ++j)
          acc[i + 4][j] = __builtin_amdgcn_mfma_f32_16x16x32_bf16(af[i], bf[j],
                                                                  acc[i + 4][j], 0, 0, 0);
    }
    __syncthreads();
  }

  // ---- pair-sum epilogue: waves 2,3 (kkh=1) donate acc via LDS (64 KB) ----
  floatx4* xch = (floatx4*)&smem[0][0];  // 4096 floatx4 = 64 KB
  if (kkh == 1) {
    #pragma unroll
    for (int i = 0; i < 8; ++i)
      #pragma unroll
      for (int j = 0; j < 4; ++j)
        xch[wc * 2048 + (i * 4 + j) * 64 + l] = acc[i][j];
  }
  __syncthreads();
  if (kkh == 0) {
    const int crow = m0 + ((l >> 4) << 2);        // + i*16 + r
    const int ccol = n0 + wc * 64 + (l & 15);     // + j*16
    #pragma unroll
    for (int j = 0; j < 4; ++j) {
      const int col = ccol + j * 16;
      const float bv = bias[col];
      #pragma unroll
      for (int i = 0; i < 8; ++i) {
        floatx4 a = acc[i][j];
        floatx4 o = xch[wc * 2048 + (i * 4 + j) * 64 + l];
        const int row = crow + i * 16;
        #pragma unroll
        for (int r = 0; r < 4; ++r) {
          float v = a[r] + o[r] + bv;
          if (MODE == 1) {
            // LIF (tau=2, v_th=1, hard reset, v0=0, T=10), constant input v:
            // v_k = v*(1-2^-k); period k1 = min k with v_k>=1; count=floor(10/k1)
            v = (v >= 2.0f)                ? 10.f
              : (v >= 1.3333333333333333f) ? 5.f
              : (v >= 1.1428571428571428f) ? 3.f
              : (v >= 1.0322580645161290f) ? 2.f
              : (v >= 1.0009775171065494f) ? 1.f : 0.f;
          }
          outb[(size_t)(row + r) * N + col] = f2bf(v);
        }
      }
    }
  }
}

// ---- 3) head: pre = 0.1*(cnt @ W_out) + b_out ; out = (pre/2 - 1 >= 0) ----
__global__ __launch_bounds__(256) void k_head(const unsigned short* __restrict__ cntb,
                                              const float* __restrict__ Wout,
                                              const float* __restrict__ bout,
                                              float* __restrict__ out) {
  __shared__ float Wl[HDIM * ADIM];  // 40 KB
  const int t = threadIdx.x;
  for (int i = t; i < HDIM * ADIM; i += 256) Wl[i] = Wout[i];
  __syncthreads();
  const int w = t >> 6, l = t & 63;
  const int row = blockIdx.x * 4 + w;
  const unsigned short* rp = cntb + (size_t)row * HDIM;
  float acc[ADIM] = {};
  #pragma unroll
  for (int it = 0; it < 4; ++it) {
    const int k0 = it * 512 + l * 8;
    short8 v = *(const short8*)(rp + k0);
    #pragma unroll
    for (int jj = 0; jj < 8; ++jj) {
      const float c = bf2f((unsigned short)v[jj]);
      const int k = k0 + jj;
      #pragma unroll
      for (int a = 0; a < ADIM; ++a) acc[a] += c * Wl[k * ADIM + a];
    }
  }
  #pragma unroll
  for (int a = 0; a < ADIM; ++a)
    #pragma unroll
    for (int off = 32; off >= 1; off >>= 1)
      acc[a] += __shfl_down(acc[a], off, 64);
  if (l == 0) {
    #pragma unroll
    for (int a = 0; a < ADIM; ++a) {
      const float pre = acc[a] * 0.1f + bout[a];
      const float vout = pre * 0.5f;  // single-step LIF from v=0: v = pre/tau
      out[(size_t)row * ADIM + a] = (vout - 1.0f >= 0.0f) ? 1.0f : 0.0f;
    }
  }
}

extern "C" void kernel_launch(void* const* d_in, const int* in_sizes, int n_in,
                              void* d_out, int out_size, void* d_ws, size_t ws_size,
                              hipStream_t stream) {
  const float* x     = (const float*)d_in[0];
  const float* W_in  = (const float*)d_in[1];
  const float* b_in  = (const float*)d_in[2];
  const float* W_snn = (const float*)d_in[3];
  const float* b_snn = (const float*)d_in[4];
  const float* W_out = (const float*)d_in[5];
  const float* b_out = (const float*)d_in[6];
  float* out = (float*)d_out;

  // workspace layout (48 MB):
  // [0,16M)   xb   : bf16 x [4096][2048]   (reused later for spike counts)
  // [16M,24M) WinT : bf16 W_in^T [2048][2048]
  // [24M,32M) WsnT : bf16 W_snn^T [2048][2048]
  // [32M,48M) hb   : bf16 h [4096][2048]
  char* ws = (char*)d_ws;
  unsigned short* xb   = (unsigned short*)(ws);
  unsigned short* WinT = (unsigned short*)(ws + (size_t)16 * 1024 * 1024);
  unsigned short* WsnT = (unsigned short*)(ws + (size_t)24 * 1024 * 1024);
  unsigned short* hb   = (unsigned short*)(ws + (size_t)32 * 1024 * 1024);
  unsigned short* cntb = xb;  // x no longer needed after GEMM1

  // 1) fused prep: cvt(8192 blocks) + transpose W_in(4096) + W_snn(4096)
  k_prep<<<16384, 256, 0, stream>>>(x, W_in, W_snn, xb, WinT, WsnT);

  // 2) h = x @ W_in + b_in  (bf16 out)
  const int gblk = (BATCH / 128) * (HDIM / 128);  // 32*16 = 512, %8==0
  k_gemm<0><<<gblk, 256, 0, stream>>>(xb, WinT, b_in, hb, BATCH, HDIM, DIN);

  // 3) cur = h @ W_snn + b_snn ; fused 10-step LIF -> spike counts
  k_gemm<1><<<gblk, 256, 0, stream>>>(hb, WsnT, b_snn, cntb, BATCH, HDIM, HDIM);

  // 4) output head + output LIF threshold
  k_head<<<BATCH / 4, 256, 0, stream>>>(cntb, W_out, b_out, out);
}